// Round 15
// baseline (213.636 us; speedup 1.0000x reference)
//
#include <hip/hip_runtime.h>
#include <hip/hip_bf16.h>
#include <cstddef>

// Problem constants (SelfAttention: B=4, T=2048, H=16, Dh=64, C=1024)
#define B_  4
#define T_  2048
#define H_  16
#define DH  64
#define C_  1024
#define BH  64    // B_*H_

typedef float  f32x16 __attribute__((ext_vector_type(16)));
typedef __bf16 bf16x8 __attribute__((ext_vector_type(8)));
typedef __bf16 bf16x4 __attribute__((ext_vector_type(4)));

#define MFMA32(a, b, c) __builtin_amdgcn_mfma_f32_32x32x16_bf16(a, b, c, 0, 0, 0)

// mfma_f32_32x32x16_bf16 layouts (cdna4_isa / m74,m101 verified C/D):
//   A[m][k]: m = lane&31, k = (lane>>5)*8 + j   (8 bf16 per lane, b128)
//   B[k][n]: n = lane&31, k = (lane>>5)*8 + j
//   C/D:     col = lane&31, row = (reg&3) + 8*(reg>>2) + 4*(lane>>5)
//
// K/V are stored FRAGMENT-MAJOR in global:
//   Kf[bh][kt64][rh][ks][lane][8]  (elem = K[kt64*64+rh*32+(lane&31)][ks*16+(lane>>5)*8+j])
//   Vf[bh][kt64][dh][c ][lane][8]  (elem = V^T[dh*32+(lane&31)][kt64*64+c*16+(lane>>5)*8+j])
// so an attention fragment load is base + lane*16B: ONE coalesced 1KB
// transaction.
//
// Session ledger: R14 = this file minus the attn V-load hoist; measured
// 211.2 us (session best; attn 89.1 / tail 122.1). R15 change: attn only --
// per rh-half, issue the 4 V fragments together with the 4 K fragments at
// the top of the iteration (~+32 transient VGPR, 64->~96 vs 128 cap), so
// V-load latency hides under the S-MFMA + softmax window instead of being
// exposed before PV. R4's prefetch test was confounded (190-reg demand vs
// 128 cap forced the allocator to sink the loads); this one fits.

__device__ __forceinline__ unsigned cvt_pk_bf16(float lo, float hi) {
    unsigned r;
    asm("v_cvt_pk_bf16_f32 %0, %1, %2" : "=v"(r) : "v"(lo), "v"(hi));
    return r;
}

// ---------------------------------------------------------------------------
// Kernel 1: QKV projection, bf16 MFMA (R13/R14 verbatim).
// ---------------------------------------------------------------------------
__global__ __launch_bounds__(256) void qkv_kernel(
    const float* __restrict__ x,
    const float* __restrict__ Wq, const float* __restrict__ bq,
    const float* __restrict__ Wk, const float* __restrict__ bk,
    const float* __restrict__ Wv, const float* __restrict__ bv,
    __bf16* __restrict__ q, __bf16* __restrict__ kf, __bf16* __restrict__ vf)
{
    __shared__ __bf16 Xs[128 * 72];          // x tile [t_local][d], bf16
    __shared__ __bf16 Ws[3][64 * 72];        // W[e][d], bf16
    __bf16* Vtl = Xs;                         // alias: V^T [e][t_local], stride 136
    __bf16* Kst = &Ws[0][0];                  // alias after mat loop: K [t_local][d], stride 72

    const int tt  = blockIdx.x;               // 0..15 (128-token tile)
    const int bh  = blockIdx.y;               // 0..63
    const int b   = bh >> 4, h = bh & 15;
    const int t0  = tt * 128;
    const int tid = threadIdx.x;
    const int wave = tid >> 6, lane = tid & 63;
    const int m = lane & 31, hh = lane >> 5;

    // stage x (fp32 -> bf16): 128 rows x 64 cols = 2048 float4 chunks
    #pragma unroll
    for (int i = 0; i < 8; ++i) {
        const int idx = i * 256 + tid;
        const int r = idx >> 4, c = (idx & 15) * 4;
        const float4 x4 = *(const float4*)(x + ((size_t)(b * T_ + t0 + r)) * C_ + h * DH + c);
        const unsigned lo = ((unsigned)__builtin_bit_cast(unsigned short, (__bf16)x4.y) << 16)
                          | (unsigned)__builtin_bit_cast(unsigned short, (__bf16)x4.x);
        const unsigned hi = ((unsigned)__builtin_bit_cast(unsigned short, (__bf16)x4.w) << 16)
                          | (unsigned)__builtin_bit_cast(unsigned short, (__bf16)x4.z);
        *(unsigned*)&Xs[r * 72 + c]     = lo;
        *(unsigned*)&Xs[r * 72 + c + 2] = hi;
    }
    // stage weights (fp32 -> bf16): 3 x 1024 float4 chunks
    #pragma unroll
    for (int i = 0; i < 4; ++i) {
        const int idx = i * 256 + tid;
        const int r = idx >> 4, c = (idx & 15) * 4;
        const float* wsrc[3] = {Wq, Wk, Wv};
        #pragma unroll
        for (int wv_ = 0; wv_ < 3; ++wv_) {
            const float4 w4 = *(const float4*)(wsrc[wv_] + r * 64 + c);
            const unsigned lo = ((unsigned)__builtin_bit_cast(unsigned short, (__bf16)w4.y) << 16)
                              | (unsigned)__builtin_bit_cast(unsigned short, (__bf16)w4.x);
            const unsigned hi = ((unsigned)__builtin_bit_cast(unsigned short, (__bf16)w4.w) << 16)
                              | (unsigned)__builtin_bit_cast(unsigned short, (__bf16)w4.z);
            *(unsigned*)&Ws[wv_][r * 72 + c]     = lo;
            *(unsigned*)&Ws[wv_][r * 72 + c + 2] = hi;
        }
    }
    __syncthreads();

    // hoist x A-fragments (wave-private rows 32*wave + m)
    bf16x8 xf[4];
    #pragma unroll
    for (int ks = 0; ks < 4; ++ks)
        xf[ks] = *(const bf16x8*)&Xs[(wave * 32 + m) * 72 + ks * 16 + hh * 8];
    __syncthreads();   // all frag reads done before Vtl aliases Xs

    // 1/sqrt(1024) * log2(e) folded into q (attention uses exp2 directly)
    const float s32 = 0.03125f * 1.4426950408889634f;

    unsigned kpk[16];   // packed k results, staged to LDS after the mat loop

    #pragma unroll
    for (int mat = 0; mat < 3; ++mat) {
        f32x16 acc0 = {}, acc1 = {};
        #pragma unroll
        for (int ks = 0; ks < 4; ++ks) {
            const bf16x8 w0 = *(const bf16x8*)&Ws[mat][(m) * 72 + ks * 16 + hh * 8];
            const bf16x8 w1 = *(const bf16x8*)&Ws[mat][(32 + m) * 72 + ks * 16 + hh * 8];
            acc0 = MFMA32(xf[ks], w0, acc0);
            acc1 = MFMA32(xf[ks], w1, acc1);
        }
        const float* bias = (mat == 0) ? bq : (mat == 1) ? bk : bv;
        const float b0 = bias[m], b1 = bias[32 + m];
        #pragma unroll
        for (int r = 0; r < 16; ++r) {
            const int R = (r & 3) + 8 * (r >> 2) + 4 * hh;   // token row in tile
            const int tloc = wave * 32 + R;
            const float v0 = acc0[r] + b0, v1 = acc1[r] + b1;
            if (mat == 0) {
                const size_t base = ((size_t)bh * T_ + t0 + tloc) * DH;
                q[base + m]      = (__bf16)(v0 * s32);
                q[base + 32 + m] = (__bf16)(v1 * s32);
            } else if (mat == 1) {
                kpk[r] = ((unsigned)__builtin_bit_cast(unsigned short, (__bf16)v1) << 16)
                       |  (unsigned)__builtin_bit_cast(unsigned short, (__bf16)v0);
            } else {
                Vtl[(m) * 136 + tloc]      = (__bf16)v0;   // V^T [e][t_local]
                Vtl[(32 + m) * 136 + tloc] = (__bf16)v1;
            }
        }
    }
    __syncthreads();   // Ws reads done (mat loop), Vtl complete

    // stage k tile [t_local][d] into Kst (Ws area, now dead)
    #pragma unroll
    for (int r = 0; r < 16; ++r) {
        const int R = (r & 3) + 8 * (r >> 2) + 4 * hh;
        const int tloc = wave * 32 + R;
        Kst[tloc * 72 + m]      = __builtin_bit_cast(__bf16, (unsigned short)(kpk[r] & 0xffff));
        Kst[tloc * 72 + 32 + m] = __builtin_bit_cast(__bf16, (unsigned short)(kpk[r] >> 16));
    }

    // Vf fragment-major out (reads Vtl; no barrier needed vs Kst region)
    #pragma unroll
    for (int i = 0; i < 4; ++i) {
        const int idx = i * 256 + tid;
        const int ln = idx & 63, c_ = idx >> 6;           // c_ 0..15
        const int kt64l = c_ >> 3, dh = (c_ >> 2) & 1, cN = c_ & 3;
        const __bf16* src = &Vtl[(dh * 32 + (ln & 31)) * 136 + kt64l * 64 + cN * 16 + (ln >> 5) * 8];
        __bf16* dst = vf + ((((size_t)(bh * 32 + tt * 2 + kt64l) * 2 + dh) * 4 + cN) * 64 + ln) * 8;
        *(uint4*)dst = *(const uint4*)src;
    }
    __syncthreads();   // Kst visible

    // Kf fragment-major out (reads Kst)
    #pragma unroll
    for (int i = 0; i < 4; ++i) {
        const int idx = i * 256 + tid;
        const int ln = idx & 63, c_ = idx >> 6;
        const int kt64l = c_ >> 3, rh = (c_ >> 2) & 1, ks = c_ & 3;
        const __bf16* src = &Kst[(kt64l * 64 + rh * 32 + (ln & 31)) * 72 + ks * 16 + (ln >> 5) * 8];
        __bf16* dst = kf + ((((size_t)(bh * 32 + tt * 2 + kt64l) * 2 + rh) * 4 + ks) * 64 + ln) * 8;
        *(uint4*)dst = *(const uint4*)src;
    }
}

// ---------------------------------------------------------------------------
// Kernel 2: flash attention. R15 change: per rh-half, K AND V fragments are
// loaded together at the top of the iteration, so V latency hides under the
// S-MFMA chain + softmax instead of stalling PV. Everything else R14.
// ---------------------------------------------------------------------------
__global__ __launch_bounds__(256, 4) void attn_kernel(
    const __bf16* __restrict__ q, const __bf16* __restrict__ kf,
    const __bf16* __restrict__ vf, __bf16* __restrict__ o)
{
    __shared__ __bf16 Os[128 * 72];          // epilogue transpose buffer

    const int bh  = blockIdx.x;              // XCD-locality axis (id%8 == bh%8)
    const int q0  = blockIdx.y * 128;
    const int tid = threadIdx.x;
    const int wave = tid >> 6, lane = tid & 63;
    const int m = lane & 31, h = lane >> 5;

    const __bf16* qb  = q  + (size_t)bh * T_ * DH;
    const __bf16* kfb = kf + (size_t)bh * (T_ * DH);   // [kt64][rh][ks][lane][8]
    const __bf16* vfb = vf + (size_t)bh * (T_ * DH);   // [kt64][dh][c ][lane][8]

    // Q fragments (one-time; [t][d] layout, segmented but negligible)
    bf16x8 qf[4];
    #pragma unroll
    for (int ks = 0; ks < 4; ++ks)
        qf[ks] = *(const bf16x8*)(qb + (size_t)(q0 + wave * 32 + m) * DH + ks * 16 + h * 8);

    f32x16 O0 = {}, O1 = {};                 // O^T [d 0..31 | 32..63][q]
    float lsum = 0.f;

    for (int kt = 0; kt < 32; ++kt) {
        const __bf16* kt_k = kfb + kt * 4096;
        const __bf16* kt_v = vfb + kt * 4096;
        #pragma unroll
        for (int rh = 0; rh < 2; ++rh) {
            // K fragments AND this rh-half's 4 V fragments issued together:
            // V latency (~200cyc L2) hides under S-MFMA + softmax (~300+cyc).
            bf16x8 kfr[4], vfr0[2], vfr1[2];
            #pragma unroll
            for (int ks = 0; ks < 4; ++ks)
                kfr[ks] = *(const bf16x8*)(kt_k + rh * 2048 + ks * 512 + lane * 8);
            #pragma unroll
            for (int cc = 0; cc < 2; ++cc) {
                const int c = rh * 2 + cc;
                vfr0[cc] = *(const bf16x8*)(kt_v + c * 512 + lane * 8);
                vfr1[cc] = *(const bf16x8*)(kt_v + 2048 + c * 512 + lane * 8);
            }
            f32x16 S = {};
            #pragma unroll
            for (int ks = 0; ks < 4; ++ks)
                S = MFMA32(kfr[ks], qf[ks], S);

            #pragma unroll
            for (int cc = 0; cc < 2; ++cc) {
                const int rb = cc * 8;
                float e0 = __builtin_amdgcn_exp2f(S[rb + 0]);
                float e1 = __builtin_amdgcn_exp2f(S[rb + 1]);
                float e2 = __builtin_amdgcn_exp2f(S[rb + 2]);
                float e3 = __builtin_amdgcn_exp2f(S[rb + 3]);
                float e4 = __builtin_amdgcn_exp2f(S[rb + 4]);
                float e5 = __builtin_amdgcn_exp2f(S[rb + 5]);
                float e6 = __builtin_amdgcn_exp2f(S[rb + 6]);
                float e7 = __builtin_amdgcn_exp2f(S[rb + 7]);
                lsum += ((e0 + e1) + (e2 + e3)) + ((e4 + e5) + (e6 + e7));
                unsigned a0 = cvt_pk_bf16(e0, e1);
                unsigned a1 = cvt_pk_bf16(e2, e3);
                unsigned b0 = cvt_pk_bf16(e4, e5);
                unsigned b1 = cvt_pk_bf16(e6, e7);
                asm("v_permlane32_swap_b32 %0, %1" : "+v"(a0), "+v"(b0));
                asm("v_permlane32_swap_b32 %0, %1" : "+v"(a1), "+v"(b1));
                const uint4 pw = {a0, a1, b0, b1};
                const bf16x8 pb = __builtin_bit_cast(bf16x8, pw);
                O0 = MFMA32(vfr0[cc], pb, O0);
                O1 = MFMA32(vfr1[cc], pb, O1);
            }
        }
    }

    // l[q]: lanes l and l+32 hold complementary kv halves of the same q-row
    lsum += __shfl_xor(lsum, 32);
    const float linv = 1.0f / lsum;

    // O^T -> LDS: lane owns q-row (wave*32 + m); reg r -> d = (r&3)+8*(r>>2)+4h
    #pragma unroll
    for (int g = 0; g < 4; ++g) {
        bf16x4 w0, w1;
        #pragma unroll
        for (int j = 0; j < 4; ++j) {
            w0[j] = (__bf16)(O0[4 * g + j] * linv);
            w1[j] = (__bf16)(O1[4 * g + j] * linv);
        }
        const int row = (wave * 32 + m) * 72;
        *(bf16x4*)&Os[row + 8 * g + 4 * h]      = w0;
        *(bf16x4*)&Os[row + 32 + 8 * g + 4 * h] = w1;
    }
    __syncthreads();

    // fully coalesced store: 128 rows x 64 bf16 = 1024 uint4 / 256 threads
    __bf16* ob = o + ((size_t)bh * T_ + q0) * DH;
    #pragma unroll
    for (int i = 0; i < 4; ++i) {
        const int idx = i * 256 + tid;
        const int r = idx >> 3, c = (idx & 7) * 8;
        *(uint4*)(ob + (size_t)r * DH + c) = *(uint4*)&Os[r * 72 + c];
    }
}

// ---------------------------------------------------------------------------
// Kernel 2.5: Wp fp32 -> bf16 pre-conversion (once; into dead q region).
// ---------------------------------------------------------------------------
__global__ __launch_bounds__(256) void wpconv_kernel(
    const float* __restrict__ Wp, __bf16* __restrict__ Wpb)
{
    const size_t idx = (size_t)(blockIdx.x * 256 + threadIdx.x) * 4;
    const float4 w4 = *(const float4*)(Wp + idx);
    const unsigned lo = ((unsigned)__builtin_bit_cast(unsigned short, (__bf16)w4.y) << 16)
                      | (unsigned)__builtin_bit_cast(unsigned short, (__bf16)w4.x);
    const unsigned hi = ((unsigned)__builtin_bit_cast(unsigned short, (__bf16)w4.w) << 16)
                      | (unsigned)__builtin_bit_cast(unsigned short, (__bf16)w4.z);
    uint2 p; p.x = lo; p.y = hi;
    *(uint2*)(Wpb + idx) = p;
}

// ---------------------------------------------------------------------------
// Kernel 3: output projection, bf16 MFMA, canonical double-buffered LDS
// (R14 verbatim -- measured win).
// ---------------------------------------------------------------------------
__global__ __launch_bounds__(256) void proj_kernel(
    const __bf16* __restrict__ a,      // [bh][t][d]
    const __bf16* __restrict__ Wpb, const float* __restrict__ bp,
    float* __restrict__ out)
{
    __shared__ __bf16 As[2][128 * 72];
    __shared__ __bf16 Bs[2][128 * 72];

    const int tb = blockIdx.x, eb = blockIdx.y;
    const int tid = threadIdx.x;
    const int wave = tid >> 6, lane = tid & 63;
    const int m = lane & 31, h = lane >> 5;
    const int tok0 = tb * 128;
    const int b = tok0 >> 11, t0 = tok0 & (T_ - 1);
    const int e0 = eb * 128;

    auto stage = [&](int buf, int cb) {
        #pragma unroll
        for (int i = 0; i < 4; ++i) {
            const int idx = i * 256 + tid;
            const int r = idx >> 3, c = (idx & 7) * 8;
            *(uint4*)&As[buf][r * 72 + c] =
                *(const uint4*)(a + ((size_t)(b * H_ + cb) * T_ + t0 + r) * DH + c);
            *(uint4*)&Bs[buf][r * 72 + c] =
                *(const uint4*)(Wpb + (size_t)(e0 + r) * C_ + cb * 64 + c);
        }
    };

    f32x16 acc[4] = {f32x16{}, f32x16{}, f32x16{}, f32x16{}};

    stage(0, 0);
    int cur = 0;
    for (int cb = 0; cb < 16; ++cb) {
        __syncthreads();               // buf[cur] staged; buf[cur^1] reads done
        if (cb < 15) stage(cur ^ 1, cb + 1);

        #pragma unroll
        for (int ks = 0; ks < 4; ++ks) {
            const bf16x8 af = *(const bf16x8*)&As[cur][(wave * 32 + m) * 72 + ks * 16 + h * 8];
            #pragma unroll
            for (int n = 0; n < 4; ++n) {
                const bf16x8 bf = *(const bf16x8*)&Bs[cur][(n * 32 + m) * 72 + ks * 16 + h * 8];
                acc[n] = MFMA32(af, bf, acc[n]);
            }
        }
        cur ^= 1;
    }

    #pragma unroll
    for (int n = 0; n < 4; ++n) {
        const int e = e0 + n * 32 + m;
        const float bias = bp[e];
        #pragma unroll
        for (int r = 0; r < 16; ++r) {
            const int R = (r & 3) + 8 * (r >> 2) + 4 * h;
            out[(size_t)(tok0 + wave * 32 + R) * C_ + e] = acc[n][r] + bias;
        }
    }
}

// ---------------------------------------------------------------------------
// Workspace (bf16): q | kf | vf | attn_out, each B*H*T*DH = 8388608 elems
// -> 64 MiB total. Wpb (2 MiB) reuses the q region (dead after attn).
// ---------------------------------------------------------------------------
extern "C" void kernel_launch(void* const* d_in, const int* in_sizes, int n_in,
                              void* d_out, int out_size, void* d_ws, size_t ws_size,
                              hipStream_t stream)
{
    const float* x  = (const float*)d_in[0];
    const float* Wq = (const float*)d_in[1];
    const float* bq = (const float*)d_in[2];
    const float* Wk = (const float*)d_in[3];
    const float* bk = (const float*)d_in[4];
    const float* Wv = (const float*)d_in[5];
    const float* bv = (const float*)d_in[6];
    const float* Wp = (const float*)d_in[7];
    const float* bp = (const float*)d_in[8];

    const size_t N = (size_t)BH * T_ * DH;
    __bf16* qws  = (__bf16*)d_ws;
    __bf16* kws  = qws + N;
    __bf16* vtws = kws + N;
    __bf16* ows  = vtws + N;
    __bf16* wpb  = qws;                 // q dead after attn; 2 MiB needed

    qkv_kernel<<<dim3(16, 64), 256, 0, stream>>>(
        x, Wq, bq, Wk, bk, Wv, bv, qws, kws, vtws);
    attn_kernel<<<dim3(64, 16), 256, 0, stream>>>(qws, kws, vtws, ows);
    wpconv_kernel<<<dim3(1024), 256, 0, stream>>>(Wp, wpb);
    proj_kernel<<<dim3(64, 8), 256, 0, stream>>>(ows, wpb, bp, (float*)d_out);
}